// Round 18
// baseline (118.119 us; speedup 1.0000x reference)
//
#include <hip/hip_runtime.h>
#include <hip/hip_bf16.h>

#define R_ 256
#define B_ 64
#define D_ 512
#define N_ 16
#define K_ 4
#define RBD (B_ * D_)          // 32768 elems per region
#define OUT_ELEMS (R_ * B_ * D_)
#define M_TOT (R_ * B_)        // 16384
#define GSLICES 32             // gram split-K slices (K-chunk 1024 fp32)
#define GPAIRS 10              // upper-triangle (bx<=by) tile pairs of 4x4
#define GBLK (GSLICES * GPAIRS)  // 320 gram blocks

typedef __attribute__((address_space(1))) unsigned int g_u32;
typedef __attribute__((address_space(3))) unsigned int l_u32;
using f32x4 = __attribute__((ext_vector_type(4))) float;
using f16x8 = __attribute__((ext_vector_type(8))) _Float16;
using f16x4 = __attribute__((ext_vector_type(4))) _Float16;

__constant__ int kBx[GPAIRS] = {0, 0, 0, 0, 1, 1, 1, 2, 2, 3};
__constant__ int kBy[GPAIRS] = {0, 1, 2, 3, 1, 2, 3, 2, 3, 3};

// ---------------------------------------------------------------------------
// Kernel 1 (gramx): merged gram + wsplit + wconv + bias, 1602 blocks.
// Blocks [0,320): fused fp32->fp16 hi/lo split + split-precision Gram over
//   the UPPER TRIANGLE of 4x4 64-row tiles (Csum symmetric in (r,j)).
//   K-chunk 1024/slice (16 kt iters). PING-PONG register prefetch: loads
//   for kt+1 issued at phase top into the idle buffer, so they span
//   cvt+barrier+MFMA (~500 cyc) instead of just MFMA. Off-diagonal blocks
//   write both orientations; diagonal blocks skip the duplicate J-stream.
//   64x64 tiles, 4 waves (2x2), 32 KB LDS, 4 blk/CU, XCD swizzle.
// Blocks [320,1344): W2p[kc][e][d] partial W2eff.
// Blocks [1344,1600): W16[e][d] = fp16(Wm[e][d]), d<512.
// Blocks [1600,1602): bias_eff[e] = b_merge[e] + b_msg . Wm2[e].
// ---------------------------------------------------------------------------
__global__ __launch_bounds__(256, 4) void gramx_kernel(
    const float* __restrict__ h, const float* __restrict__ Wm,
    const float* __restrict__ Wmsg, const float* __restrict__ b_msg,
    const float* __restrict__ b_merge, _Float16* __restrict__ A16,
    float* __restrict__ Cp, float* __restrict__ W2p,
    _Float16* __restrict__ W16, float* __restrict__ bias_eff) {
  __shared__ char smem[32768];
  const int t = threadIdx.x;
  const int bid = blockIdx.x;

  if (bid >= GBLK) {
    if (bid >= 1600) {
      const int e = (bid - 1600) * 256 + t;  // 0..511
      const float4* bp = (const float4*)b_msg;
      const float4* wp = (const float4*)&Wm[(size_t)e * 1024 + 512];
      float acc = 0.f;
      for (int c = 0; c < 128; c++) {
        float4 b4 = bp[c], w4 = wp[c];
        acc += b4.x * w4.x + b4.y * w4.y + b4.z * w4.z + b4.w * w4.w;
      }
      bias_eff[e] = acc + b_merge[e];
      return;
    }
    if (bid >= 1344) {
      const int i = (bid - 1344) * 256 + t;  // 0..65535 float4 ids
      const int e = i >> 7;
      const int c4 = (i & 127) * 4;
      float4 v = *(const float4*)&Wm[(size_t)e * 1024 + c4];
      f16x4 o = {(_Float16)v.x, (_Float16)v.y, (_Float16)v.z, (_Float16)v.w};
      *(f16x4*)&W16[(size_t)e * 1024 + c4] = o;
      return;
    }
    // ---------------- wsplit part ----------------
    const int gid = bid - GBLK;                // 0..1023
    const int db = (gid & 15) * 32;
    const int eb = ((gid >> 4) & 15) * 32;
    const int kc = gid >> 8;                   // 0..3
    float(*As)[33] = (float(*)[33])smem;
    float(*Bs)[33] = (float(*)[33])(smem + 32 * 33 * 4);
    const int tx = t % 16, ty = t / 16;
    const int lr = t / 8;
    const int lc = (t % 8) * 4;
    float a00 = 0.f, a01 = 0.f, a10 = 0.f, a11 = 0.f;
    for (int c0 = kc * 128; c0 < kc * 128 + 128; c0 += 32) {
      float4 av = *(const float4*)&Wm[(size_t)(eb + lr) * 1024 + 512 + c0 + lc];
      float4 bv = *(const float4*)&Wmsg[(size_t)(c0 + lr) * 512 + db + lc];
      As[lr][lc + 0] = av.x; As[lr][lc + 1] = av.y;
      As[lr][lc + 2] = av.z; As[lr][lc + 3] = av.w;
      Bs[lr][lc + 0] = bv.x; Bs[lr][lc + 1] = bv.y;
      Bs[lr][lc + 2] = bv.z; Bs[lr][lc + 3] = bv.w;
      __syncthreads();
#pragma unroll
      for (int kk = 0; kk < 32; kk++) {
        float x0 = As[2 * ty + 0][kk], x1 = As[2 * ty + 1][kk];
        float y0 = Bs[kk][2 * tx + 0], y1 = Bs[kk][2 * tx + 1];
        a00 += x0 * y0; a01 += x0 * y1;
        a10 += x1 * y0; a11 += x1 * y1;
      }
      __syncthreads();
    }
    float* base = W2p + (size_t)kc * 512 * 512;
    base[(size_t)(eb + 2 * ty + 0) * 512 + db + 2 * tx + 0] = a00;
    base[(size_t)(eb + 2 * ty + 0) * 512 + db + 2 * tx + 1] = a01;
    base[(size_t)(eb + 2 * ty + 1) * 512 + db + 2 * tx + 0] = a10;
    base[(size_t)(eb + 2 * ty + 1) * 512 + db + 2 * tx + 1] = a11;
    return;
  }

  // ---------------- gram part (upper triangle) ----------------
  const int work = (bid & 7) * (GBLK / 8) + (bid >> 3);
  const int s = work / GPAIRS;                // 0..31 (4 per XCD)
  const int pr = work % GPAIRS;
  const int bx = kBx[pr];
  const int by = kBy[pr];
  const int I = bx * 64;
  const int J = by * 64;
  const bool duty = (bx == by);
  const int lane = t & 63;
  const int w = t >> 6;                       // 0..3
  char* sHiI = smem;                          // 64 x 128 B = 8 KB each
  char* sHiJ = smem + 8192;
  char* sLoJ = smem + 16384;
  char* sLoI = smem + 24576;
  const int wm = w >> 1, wn = w & 1;
  const int rlane = lane & 15;
  const int kq = lane >> 4;

  f32x4 c1[2][2] = {};
  f32x4 c2[2][2] = {};
  f32x4 c3[2][2] = {};

  const float* hI = h + (size_t)I * RBD + (size_t)s * 1024;
  const float* hJ = h + (size_t)J * RBD + (size_t)s * 1024;
  const int frow = t >> 4;                    // staging row base (per u: +16)
  const int fc4 = t & 15;                     // float4-chunk in 64-col tile

#define G_LOAD(RI, RJ, KT)                                                     \
  {                                                                            \
    _Pragma("unroll") for (int u = 0; u < 4; ++u) {                            \
      const int row = u * 16 + frow;                                           \
      RI[u] = *(const float4*)&hI[(size_t)row * RBD + (KT) * 64 + fc4 * 4];    \
      if (!duty)                                                               \
        RJ[u] = *(const float4*)&hJ[(size_t)row * RBD + (KT) * 64 + fc4 * 4];  \
    }                                                                          \
  }

#define G_CVT(RI, RJ, KT)                                                      \
  {                                                                            \
    _Pragma("unroll") for (int u = 0; u < 4; ++u) {                            \
      const int row = u * 16 + frow;                                           \
      const int boff =                                                         \
          row * 128 + (((fc4 >> 1) ^ (row & 7)) << 4) + (fc4 & 1) * 8;         \
      float4 vI = RI[u];                                                       \
      f16x4 hiI = {(_Float16)vI.x, (_Float16)vI.y, (_Float16)vI.z,             \
                   (_Float16)vI.w};                                            \
      f16x4 loI = {(_Float16)(vI.x - (float)hiI[0]),                           \
                   (_Float16)(vI.y - (float)hiI[1]),                           \
                   (_Float16)(vI.z - (float)hiI[2]),                           \
                   (_Float16)(vI.w - (float)hiI[3])};                          \
      *(f16x4*)(sHiI + boff) = hiI;                                            \
      *(f16x4*)(sLoI + boff) = loI;                                            \
      if (duty) {                                                              \
        *(f16x4*)(sHiJ + boff) = hiI;                                          \
        *(f16x4*)(sLoJ + boff) = loI;                                          \
        *(f16x4*)&A16[(size_t)(J + row) * RBD + (size_t)s * 1024 +             \
                      (KT) * 64 + fc4 * 4] = hiI;                              \
      } else {                                                                 \
        float4 vJ = RJ[u];                                                     \
        f16x4 hiJ = {(_Float16)vJ.x, (_Float16)vJ.y, (_Float16)vJ.z,           \
                     (_Float16)vJ.w};                                          \
        f16x4 loJ = {(_Float16)(vJ.x - (float)hiJ[0]),                         \
                     (_Float16)(vJ.y - (float)hiJ[1]),                         \
                     (_Float16)(vJ.z - (float)hiJ[2]),                         \
                     (_Float16)(vJ.w - (float)hiJ[3])};                        \
        *(f16x4*)(sHiJ + boff) = hiJ;                                          \
        *(f16x4*)(sLoJ + boff) = loJ;                                          \
      }                                                                        \
    }                                                                          \
  }

#define G_MFMA()                                                               \
  {                                                                            \
    _Pragma("unroll") for (int ks = 0; ks < 2; ++ks) {                         \
      f16x8 ai[2], li[2], bj[2], lj[2];                                        \
      _Pragma("unroll") for (int i = 0; i < 2; ++i) {                          \
        const int row = wm * 32 + i * 16 + rlane;                              \
        const int slot = (ks * 4 + kq) ^ (row & 7);                            \
        ai[i] = *(const f16x8*)(sHiI + row * 128 + slot * 16);                 \
        li[i] = *(const f16x8*)(sLoI + row * 128 + slot * 16);                 \
      }                                                                        \
      _Pragma("unroll") for (int j = 0; j < 2; ++j) {                          \
        const int row = wn * 32 + j * 16 + rlane;                              \
        const int slot = (ks * 4 + kq) ^ (row & 7);                            \
        bj[j] = *(const f16x8*)(sHiJ + row * 128 + slot * 16);                 \
        lj[j] = *(const f16x8*)(sLoJ + row * 128 + slot * 16);                 \
      }                                                                        \
      _Pragma("unroll") for (int i = 0; i < 2; ++i)                            \
          _Pragma("unroll") for (int j = 0; j < 2; ++j) {                      \
        c1[i][j] = __builtin_amdgcn_mfma_f32_16x16x32_f16(ai[i], bj[j],        \
                                                          c1[i][j], 0, 0, 0);  \
        c2[i][j] = __builtin_amdgcn_mfma_f32_16x16x32_f16(ai[i], lj[j],        \
                                                          c2[i][j], 0, 0, 0);  \
        c3[i][j] = __builtin_amdgcn_mfma_f32_16x16x32_f16(li[i], bj[j],        \
                                                          c3[i][j], 0, 0, 0);  \
      }                                                                        \
    }                                                                          \
  }

  float4 rIA[4], rJA[4], rIB[4], rJB[4];
  G_LOAD(rIA, rJA, 0);
  for (int kt2 = 0; kt2 < 16; kt2 += 2) {
    // even step: consume A, prefetch kt2+1 into B (spans cvt+bar+MFMA)
    if (kt2) __syncthreads();       // prior MFMA reads done before overwrite
    G_LOAD(rIB, rJB, kt2 + 1);
    G_CVT(rIA, rJA, kt2);
    __syncthreads();
    G_MFMA();
    // odd step: consume B, prefetch kt2+2 into A
    __syncthreads();
    if (kt2 + 2 < 16) G_LOAD(rIA, rJA, kt2 + 2);
    G_CVT(rIB, rJB, kt2 + 1);
    __syncthreads();
    G_MFMA();
  }
#undef G_LOAD
#undef G_CVT
#undef G_MFMA

  f32x4 cs[2][2];
#pragma unroll
  for (int i = 0; i < 2; ++i)
#pragma unroll
    for (int j = 0; j < 2; ++j)
      cs[i][j] = c1[i][j] + c2[i][j] + c3[i][j];

  // normal orientation
#pragma unroll
  for (int i = 0; i < 2; ++i) {
#pragma unroll
    for (int reg = 0; reg < 4; ++reg) {
      const int gr = I + wm * 32 + i * 16 + kq * 4 + reg;
      const size_t base = ((size_t)s * 256 + gr) * 256 + J + wn * 32 + rlane;
#pragma unroll
      for (int j = 0; j < 2; ++j) Cp[base + j * 16] = cs[i][j][reg];
    }
  }
  // transposed orientation (off-diagonal only): float4 per lane
  if (!duty) {
#pragma unroll
    for (int i = 0; i < 2; ++i)
#pragma unroll
      for (int j = 0; j < 2; ++j) {
        const int gc = J + wn * 32 + j * 16 + rlane;
        const int gr0 = I + wm * 32 + i * 16 + kq * 4;
        *(f32x4*)&Cp[((size_t)s * 256 + gc) * 256 + gr0] = cs[i][j];
      }
  }
}

// ---------------------------------------------------------------------------
// Kernel 2 (fin): fused reduce+topk+neighbor-mean and W2 finisher,
// 1280 blocks x 256 thr. (R16 version, GSLICES=32)
// ---------------------------------------------------------------------------
__global__ __launch_bounds__(256) void fin_kernel(
    const float* __restrict__ Cp, const int* __restrict__ nbrs,
    const float* __restrict__ W2p, const _Float16* __restrict__ A16,
    _Float16* __restrict__ Am16, int* __restrict__ sel,
    float* __restrict__ fanin, _Float16* __restrict__ W16) {
  const int bx = blockIdx.x;
  const int t = threadIdx.x;
  if (bx < 256) {
    const int r = bx;
    __shared__ float sims_all[256];
    __shared__ int nb_s[N_];
    __shared__ int sel_sm[K_];
    const float* base = Cp + (size_t)r * 256 + t;
    float acc = 0.f;
#pragma unroll 8
    for (int s = 0; s < GSLICES; ++s) acc += base[(size_t)s * 65536];
    sims_all[t] = acc;
    if (t < N_) nb_s[t] = nbrs[r * N_ + t];
    __syncthreads();
    if (t == 0) {
      float sims_s[N_];
#pragma unroll
      for (int n = 0; n < N_; ++n) sims_s[n] = sims_all[nb_s[n]];
      unsigned used = 0;
#pragma unroll
      for (int k = 0; k < K_; k++) {
        float best = -3.0e38f;
        int bi = 0;
        for (int nn = 0; nn < N_; nn++) {
          if (used & (1u << nn)) continue;
          float vv = sims_s[nn];
          if (vv > best) { best = vv; bi = nn; }
        }
        used |= 1u << bi;
        const int sj = nb_s[bi];
        sel[r * K_ + k] = sj;
        sel_sm[k] = sj;
      }
      if (r == 0) *fanin = 4.0f;
    }
    __syncthreads();
    const _Float16* g0 = A16 + (size_t)sel_sm[0] * RBD;
    const _Float16* g1 = A16 + (size_t)sel_sm[1] * RBD;
    const _Float16* g2 = A16 + (size_t)sel_sm[2] * RBD;
    const _Float16* g3 = A16 + (size_t)sel_sm[3] * RBD;
    _Float16* dst = Am16 + (size_t)r * RBD;
#pragma unroll 4
    for (int i = t; i < RBD / 8; i += 256) {  // 4096 f16x8 chunks
      const size_t off = (size_t)i * 8;
      f16x8 q0 = *(const f16x8*)&g0[off];
      f16x8 q1 = *(const f16x8*)&g1[off];
      f16x8 q2 = *(const f16x8*)&g2[off];
      f16x8 q3 = *(const f16x8*)&g3[off];
      f16x8 m = ((q0 + q1) + (q2 + q3)) * (_Float16)0.25f;
      *(f16x8*)&dst[off] = m;
    }
  } else {
    const int i = (bx - 256) * 256 + t;
    const int e = i >> 9;
    const int d = i & 511;
    float acc = 0.f;
#pragma unroll
    for (int kc = 0; kc < 4; ++kc)
      acc += W2p[(size_t)kc * 512 * 512 + (size_t)e * 512 + d];
    W16[(size_t)e * 1024 + 512 + d] = (_Float16)acc;
  }
}

// ---------------------------------------------------------------------------
// Kernel 3: fp16 MFMA GEMM, 2-phase pipelined (unchanged from round 16).
// ---------------------------------------------------------------------------
__global__ __launch_bounds__(512, 2) void mfma_gemm_kernel(
    const _Float16* __restrict__ A16, const _Float16* __restrict__ Am16,
    const _Float16* __restrict__ W16, const float* __restrict__ bias,
    float* __restrict__ out) {
  const int t = threadIdx.x;
  const int lane = t & 63;
  const int w = t >> 6;                  // 0..7
  const int bid = blockIdx.x;
  const int work = (bid & 7) * 64 + (bid >> 3);
  const int eb = (work & 3) * 128;
  const int mt = work >> 2;              // 0..127
  const int m0 = mt * 128;
  __shared__ char smemA[2][128 * 128];   // 32 KB
  __shared__ char smemW[2][128 * 128];   // 32 KB
  const int wm = w >> 2, wn = w & 3;
  const int rlane = lane & 15;
  const int kq = lane >> 4;

  f32x4 acc[4][2] = {};

  const char* Ab = (const char*)A16;
  const char* Amb = (const char*)Am16;
  const char* Wb = (const char*)W16;

  const int f0 = t, f1 = 512 + t;
  const int row0 = f0 >> 3, slot0 = (f0 & 7) ^ (row0 & 7);
  const int row1 = f1 >> 3, slot1 = (f1 & 7) ^ (row1 & 7);

#define GEMM_STAGE(buf, kt)                                                    \
  {                                                                            \
    const char* ga0 =                                                          \
        ((kt) < 8)                                                             \
            ? Ab + ((size_t)(m0 + row0) * 1024 + (kt) * 128 + slot0 * 16)      \
            : Amb +                                                            \
                  ((size_t)(m0 + row0) * 1024 + ((kt)-8) * 128 + slot0 * 16);  \
    __builtin_amdgcn_global_load_lds((const g_u32*)ga0,                        \
                                     (l_u32*)(smemA[buf] + w * 1024), 16, 0,   \
                                     0);                                       \
    const char* gw0 =                                                          \
        Wb + ((size_t)(eb + row0) * 2048 + (kt) * 128 + slot0 * 16);           \
    __builtin_amdgcn_global_load_lds((const g_u32*)gw0,                        \
                                     (l_u32*)(smemW[buf] + w * 1024), 16, 0,   \
                                     0);                                       \
    const char* ga1 =                                                          \
        ((kt) < 8)                                                             \
            ? Ab + ((size_t)(m0 + row1) * 1024 + (kt) * 128 + slot1 * 16)      \
            : Amb +                                                            \
                  ((size_t)(m0 + row1) * 1024 + ((kt)-8) * 128 + slot1 * 16);  \
    __builtin_amdgcn_global_load_lds(                                          \
        (const g_u32*)ga1, (l_u32*)(smemA[buf] + 8192 + w * 1024), 16, 0, 0);  \
    const char* gw1 =                                                          \
        Wb + ((size_t)(eb + row1) * 2048 + (kt) * 128 + slot1 * 16);           \
    __builtin_amdgcn_global_load_lds(                                          \
        (const g_u32*)gw1, (l_u32*)(smemW[buf] + 8192 + w * 1024), 16, 0, 0);  \
  }

  GEMM_STAGE(0, 0);
  __syncthreads();  // buf0 ready (compiler drains vmcnt before barrier)

  int cur = 0;
  for (int kt = 0; kt < 16; ++kt) {
    if (kt < 15) GEMM_STAGE(cur ^ 1, kt + 1);  // next-tile loads in flight
    // ---- compute from buf[cur] ----
#pragma unroll
    for (int ks = 0; ks < 2; ++ks) {
      f16x8 a[4], b[2];
#pragma unroll
      for (int i = 0; i < 4; ++i) {
        const int row = wm * 64 + i * 16 + rlane;
        const int slot = (ks * 4 + kq) ^ (row & 7);
        a[i] = *(const f16x8*)(smemA[cur] + row * 128 + slot * 16);
      }
#pragma unroll
      for (int j = 0; j < 2; ++j) {
        const int row = wn * 32 + j * 16 + rlane;
        const int slot = (ks * 4 + kq) ^ (row & 7);
        b[j] = *(const f16x8*)(smemW[cur] + row * 128 + slot * 16);
      }
#pragma unroll
      for (int i = 0; i < 4; ++i)
#pragma unroll
        for (int j = 0; j < 2; ++j)
          acc[i][j] = __builtin_amdgcn_mfma_f32_16x16x32_f16(a[i], b[j],
                                                             acc[i][j], 0, 0, 0);
    }
    __syncthreads();  // drains next-tile loads; orders reads before overwrite
    cur ^= 1;
  }
#undef GEMM_STAGE

  float bj[2];
#pragma unroll
  for (int j = 0; j < 2; ++j) bj[j] = bias[eb + wn * 32 + j * 16 + rlane];
#pragma unroll
  for (int i = 0; i < 4; ++i) {
#pragma unroll
    for (int reg = 0; reg < 4; ++reg) {
      const size_t m = (size_t)m0 + wm * 64 + i * 16 + kq * 4 + reg;
      float* po = out + m * 512 + eb + wn * 32 + rlane;
#pragma unroll
      for (int j = 0; j < 2; ++j) po[j * 16] = acc[i][j][reg] + bj[j];
    }
  }
}

// ---------------------------------------------------------------------------
// Fallback fp32 path (small workspace): round-1 kernels.
// ---------------------------------------------------------------------------
__global__ __launch_bounds__(256) void bias_kernel(
    const float* __restrict__ Wm, const float* __restrict__ b_msg,
    const float* __restrict__ b_merge, float* __restrict__ bias_eff) {
  const int e = blockIdx.x * 256 + threadIdx.x;
  const float4* bp = (const float4*)b_msg;
  const float4* wp = (const float4*)&Wm[(size_t)e * 1024 + 512];
  float acc = 0.f;
  for (int c = 0; c < 128; c++) {
    float4 b4 = bp[c], w4 = wp[c];
    acc += b4.x * w4.x + b4.y * w4.y + b4.z * w4.z + b4.w * w4.w;
  }
  bias_eff[e] = acc + b_merge[e];
}

__global__ __launch_bounds__(256) void sims_topk_kernel(
    const float* __restrict__ h, const int* __restrict__ nbrs,
    int* __restrict__ sel, float* __restrict__ fanin) {
  const int r = blockIdx.x;
  const int t = threadIdx.x;
  const int lane = t & 63;
  const int wave = t >> 6;
  __shared__ float sims_s[N_];
  __shared__ int nb_s[N_];
  if (t < N_) nb_s[t] = nbrs[r * N_ + t];
  __syncthreads();
  const int n0 = wave * 4;
  const float4* hr  = (const float4*)(h + (size_t)r * RBD);
  const float4* hn0 = (const float4*)(h + (size_t)nb_s[n0 + 0] * RBD);
  const float4* hn1 = (const float4*)(h + (size_t)nb_s[n0 + 1] * RBD);
  const float4* hn2 = (const float4*)(h + (size_t)nb_s[n0 + 2] * RBD);
  const float4* hn3 = (const float4*)(h + (size_t)nb_s[n0 + 3] * RBD);
  float a0 = 0.f, a1 = 0.f, a2 = 0.f, a3 = 0.f;
  for (int i = lane; i < RBD / 4; i += 64) {
    float4 x = hr[i];
    float4 y0 = hn0[i], y1 = hn1[i], y2 = hn2[i], y3 = hn3[i];
    a0 += x.x * y0.x + x.y * y0.y + x.z * y0.z + x.w * y0.w;
    a1 += x.x * y1.x + x.y * y1.y + x.z * y1.z + x.w * y1.w;
    a2 += x.x * y2.x + x.y * y2.y + x.z * y2.z + x.w * y2.w;
    a3 += x.x * y3.x + x.y * y3.y + x.z * y3.z + x.w * y3.w;
  }
  float v[4] = {a0, a1, a2, a3};
#pragma unroll
  for (int n = 0; n < 4; n++) {
    float x = v[n];
#pragma unroll
    for (int off = 32; off > 0; off >>= 1) x += __shfl_down(x, off);
    if (lane == 0) sims_s[n0 + n] = x;
  }
  __syncthreads();
  if (t == 0) {
    unsigned used = 0;
#pragma unroll
    for (int k = 0; k < K_; k++) {
      float best = -3.0e38f;
      int bi = 0;
      for (int n = 0; n < N_; n++) {
        if (used & (1u << n)) continue;
        float vv = sims_s[n];
        if (vv > best) { best = vv; bi = n; }
      }
      used |= 1u << bi;
      sel[r * K_ + k] = nb_s[bi];
    }
    if (r == 0) *fanin = 4.0f;
  }
}

__global__ __launch_bounds__(256) void w2eff_f32_kernel(
    const float* __restrict__ Wm, const float* __restrict__ Wmsg,
    float* __restrict__ W2) {
  __shared__ float As[32][33];
  __shared__ float Bs[32][33];
  const int t = threadIdx.x;
  const int eb = blockIdx.y * 32;
  const int db = blockIdx.x * 32;
  const int tx = t % 16, ty = t / 16;
  const int lr = t / 8;
  const int lc = (t % 8) * 4;
  float a00 = 0.f, a01 = 0.f, a10 = 0.f, a11 = 0.f;
  for (int c0 = 0; c0 < 512; c0 += 32) {
    float4 av = *(const float4*)&Wm[(size_t)(eb + lr) * 1024 + 512 + c0 + lc];
    float4 bv = *(const float4*)&Wmsg[(size_t)(c0 + lr) * 512 + db + lc];
    As[lr][lc + 0] = av.x; As[lr][lc + 1] = av.y;
    As[lr][lc + 2] = av.z; As[lr][lc + 3] = av.w;
    Bs[lr][lc + 0] = bv.x; Bs[lr][lc + 1] = bv.y;
    Bs[lr][lc + 2] = bv.z; Bs[lr][lc + 3] = bv.w;
    __syncthreads();
#pragma unroll
    for (int kk = 0; kk < 32; kk++) {
      float x0 = As[2 * ty + 0][kk], x1 = As[2 * ty + 1][kk];
      float y0 = Bs[kk][2 * tx + 0], y1 = Bs[kk][2 * tx + 1];
      a00 += x0 * y0; a01 += x0 * y1;
      a10 += x1 * y0; a11 += x1 * y1;
    }
    __syncthreads();
  }
  W2[(size_t)(eb + 2 * ty + 0) * 512 + db + 2 * tx + 0] = a00;
  W2[(size_t)(eb + 2 * ty + 0) * 512 + db + 2 * tx + 1] = a01;
  W2[(size_t)(eb + 2 * ty + 1) * 512 + db + 2 * tx + 0] = a10;
  W2[(size_t)(eb + 2 * ty + 1) * 512 + db + 2 * tx + 1] = a11;
}

__global__ __launch_bounds__(256) void fused_gemm_f32_kernel(
    const float* __restrict__ h, const int* __restrict__ sel,
    const float* __restrict__ Wm, const float* __restrict__ W2,
    const float* __restrict__ bias_eff, float* __restrict__ out) {
  const int r = blockIdx.y;
  const int eb = blockIdx.x * 256;
  const int t = threadIdx.x;
  __shared__ float As[64][33];
  __shared__ float Ws[256][33];
  __shared__ int sel_s[K_];
  if (t < K_) sel_s[t] = sel[r * K_ + t];
  __syncthreads();
  const size_t hr = (size_t)r * RBD;
  const size_t s0 = (size_t)sel_s[0] * RBD;
  const size_t s1 = (size_t)sel_s[1] * RBD;
  const size_t s2 = (size_t)sel_s[2] * RBD;
  const size_t s3 = (size_t)sel_s[3] * RBD;
  const int tb = t % 8;
  const int te = t / 8;
  const int ab = t / 4;
  const int ac = (t % 4) * 8;
  float acc[8][8] = {};
  for (int d0 = 0; d0 < 1024; d0 += 32) {
    if (d0 < 512) {
      const float* src = h + hr + (size_t)ab * 512 + d0 + ac;
      float4 v0 = *(const float4*)(src);
      float4 v1 = *(const float4*)(src + 4);
      As[ab][ac + 0] = v0.x; As[ab][ac + 1] = v0.y;
      As[ab][ac + 2] = v0.z; As[ab][ac + 3] = v0.w;
      As[ab][ac + 4] = v1.x; As[ab][ac + 5] = v1.y;
      As[ab][ac + 6] = v1.z; As[ab][ac + 7] = v1.w;
    } else {
      const size_t off = (size_t)ab * 512 + (d0 - 512) + ac;
      const float* p0 = h + s0 + off;
      const float* p1 = h + s1 + off;
      const float* p2 = h + s2 + off;
      const float* p3 = h + s3 + off;
      float4 q0 = *(const float4*)p0, q0b = *(const float4*)(p0 + 4);
      float4 q1 = *(const float4*)p1, q1b = *(const float4*)(p1 + 4);
      float4 q2 = *(const float4*)p2, q2b = *(const float4*)(p2 + 4);
      float4 q3 = *(const float4*)p3, q3b = *(const float4*)(p3 + 4);
      As[ab][ac + 0] = 0.25f * (q0.x + q1.x + q2.x + q3.x);
      As[ab][ac + 1] = 0.25f * (q0.y + q1.y + q2.y + q3.y);
      As[ab][ac + 2] = 0.25f * (q0.z + q1.z + q2.z + q3.z);
      As[ab][ac + 3] = 0.25f * (q0.w + q1.w + q2.w + q3.w);
      As[ab][ac + 4] = 0.25f * (q0b.x + q1b.x + q2b.x + q3b.x);
      As[ab][ac + 5] = 0.25f * (q0b.y + q1b.y + q2b.y + q3b.y);
      As[ab][ac + 6] = 0.25f * (q0b.z + q1b.z + q2b.z + q3b.z);
      As[ab][ac + 7] = 0.25f * (q0b.w + q1b.w + q2b.w + q3b.w);
    }
    {
      const float* src = (d0 < 512)
          ? (Wm + (size_t)(eb + t) * 1024 + d0)
          : (W2 + (size_t)(eb + t) * 512 + (d0 - 512));
#pragma unroll
      for (int j = 0; j < 8; j++) {
        float4 v = *(const float4*)(src + 4 * j);
        Ws[t][4 * j + 0] = v.x; Ws[t][4 * j + 1] = v.y;
        Ws[t][4 * j + 2] = v.z; Ws[t][4 * j + 3] = v.w;
      }
    }
    __syncthreads();
#pragma unroll
    for (int kk = 0; kk < 32; kk++) {
      float a[8], wv[8];
#pragma unroll
      for (int i = 0; i < 8; i++) a[i] = As[tb + 8 * i][kk];
#pragma unroll
      for (int j = 0; j < 8; j++) wv[j] = Ws[te + 32 * j][kk];
#pragma unroll
      for (int i = 0; i < 8; i++)
#pragma unroll
        for (int j = 0; j < 8; j++) acc[i][j] += a[i] * wv[j];
    }
    __syncthreads();
  }
  float be[8];
#pragma unroll
  for (int j = 0; j < 8; j++) be[j] = bias_eff[eb + te + 32 * j];
#pragma unroll
  for (int i = 0; i < 8; i++) {
    const int b = tb + 8 * i;
#pragma unroll
    for (int j = 0; j < 8; j++) {
      const int e = eb + te + 32 * j;
      out[hr + (size_t)b * 512 + e] = acc[i][j] + be[j];
    }
  }
}

// ---------------------------------------------------------------------------
extern "C" void kernel_launch(void* const* d_in, const int* in_sizes, int n_in,
                              void* d_out, int out_size, void* d_ws,
                              size_t ws_size, hipStream_t stream) {
  const float* h       = (const float*)d_in[0];
  const int*   nbrs    = (const int*)d_in[1];
  const float* W_msg   = (const float*)d_in[2];
  const float* b_msg   = (const float*)d_in[3];
  const float* W_merge = (const float*)d_in[4];
  const float* b_merge = (const float*)d_in[5];
  float* out = (float*)d_out;
  char* ws = (char*)d_ws;

  const size_t SZ_PART = (size_t)GSLICES * 256 * 256 * 4;  // 8.39 MB
  const size_t SZ_A = (size_t)M_TOT * 512 * 2;             // 16.78 MB each
  const size_t SZ_W = (size_t)512 * 1024 * 2;              // 1 MB
  const size_t SZ_W2P = (size_t)4 * 512 * 512 * 4;         // 4 MB
  size_t off = 0;
  int*      sel      = (int*)(ws + off);      off += 4096;
  float*    bias_eff = (float*)(ws + off);    off += 4096;
  float*    Cp       = (float*)(ws + off);    off += SZ_PART;
  _Float16* A16      = (_Float16*)(ws + off); off += SZ_A;
  _Float16* Am16     = (_Float16*)(ws + off); off += SZ_A;
  _Float16* W16      = (_Float16*)(ws + off); off += SZ_W;
  float*    W2p      = (float*)(ws + off);    off += SZ_W2P;
  const size_t NEED = off;

  if (ws_size >= NEED) {
    gramx_kernel<<<1602, 256, 0, stream>>>(h, W_merge, W_msg, b_msg, b_merge,
                                           A16, Cp, W2p, W16, bias_eff);
    fin_kernel<<<1280, 256, 0, stream>>>(Cp, nbrs, W2p, A16, Am16, sel,
                                         out + OUT_ELEMS, W16);
    mfma_gemm_kernel<<<512, 512, 0, stream>>>(A16, Am16, W16, bias_eff, out);
  } else {
    int*   fsel     = (int*)ws;
    float* W2       = (float*)(ws + 4096);
    float* fbias    = (float*)(ws + 4096 + 512 * 512 * 4);
    sims_topk_kernel<<<R_, 256, 0, stream>>>(h, nbrs, fsel, out + OUT_ELEMS);
    bias_kernel<<<2, 256, 0, stream>>>(W_merge, b_msg, b_merge, fbias);
    w2eff_f32_kernel<<<dim3(16, 16), 256, 0, stream>>>(W_merge, W_msg, W2);
    fused_gemm_f32_kernel<<<dim3(2, R_), 256, 0, stream>>>(h, fsel, W_merge,
                                                           W2, fbias, out);
  }
}

// Round 19
// 74.750 us; speedup vs baseline: 1.5802x; 1.5802x over previous
//
#include <hip/hip_runtime.h>
#include <hip/hip_bf16.h>

#define R_ 256
#define B_ 64
#define D_ 512
#define N_ 16
#define K_ 4
#define RBD (B_ * D_)          // 32768 elems per region
#define OUT_ELEMS (R_ * B_ * D_)
#define M_TOT (R_ * B_)        // 16384
#define GSLICES 32             // gram split-K slices (K-chunk 1024 fp32)
#define GPAIRS 10              // upper-triangle (bx<=by) tile pairs of 4x4
#define GBLK (GSLICES * GPAIRS)  // 320 gram blocks

typedef __attribute__((address_space(1))) unsigned int g_u32;
typedef __attribute__((address_space(3))) unsigned int l_u32;
using f32x4 = __attribute__((ext_vector_type(4))) float;
using f16x8 = __attribute__((ext_vector_type(8))) _Float16;
using f16x4 = __attribute__((ext_vector_type(4))) _Float16;

__constant__ int kBx[GPAIRS] = {0, 0, 0, 0, 1, 1, 1, 2, 2, 3};
__constant__ int kBy[GPAIRS] = {0, 1, 2, 3, 1, 2, 3, 2, 3, 3};

// ---------------------------------------------------------------------------
// Kernel 1 (gramx): merged gram + wsplit + wconv + bias, 1602 blocks.
// Blocks [0,320): fused fp32->fp16 hi/lo split + split-precision Gram over
//   the UPPER TRIANGLE of 4x4 64-row tiles (Csum symmetric in (r,j)).
//   K-chunk 1024/slice (16 kt iters). Off-diagonal blocks write both
//   orientations. Diagonal blocks skip the duplicate J-stream (reuse rI —
//   bitwise identical). 64x64 tiles, 4 waves (2x2), 32 KB LDS, 4 blk/CU.
//   XCD swizzle; T14 prefetch; A16 duty on diagonal.
// Blocks [320,1344): W2p[kc][e][d] partial W2eff.
// Blocks [1344,1600): W16[e][d] = fp16(Wm[e][d]), d<512.
// Blocks [1600,1602): bias_eff[e] = b_merge[e] + b_msg . Wm2[e].
// ---------------------------------------------------------------------------
__global__ __launch_bounds__(256, 4) void gramx_kernel(
    const float* __restrict__ h, const float* __restrict__ Wm,
    const float* __restrict__ Wmsg, const float* __restrict__ b_msg,
    const float* __restrict__ b_merge, _Float16* __restrict__ A16,
    float* __restrict__ Cp, float* __restrict__ W2p,
    _Float16* __restrict__ W16, float* __restrict__ bias_eff) {
  __shared__ char smem[32768];
  const int t = threadIdx.x;
  const int bid = blockIdx.x;

  if (bid >= GBLK) {
    if (bid >= 1600) {
      const int e = (bid - 1600) * 256 + t;  // 0..511
      const float4* bp = (const float4*)b_msg;
      const float4* wp = (const float4*)&Wm[(size_t)e * 1024 + 512];
      float acc = 0.f;
      for (int c = 0; c < 128; c++) {
        float4 b4 = bp[c], w4 = wp[c];
        acc += b4.x * w4.x + b4.y * w4.y + b4.z * w4.z + b4.w * w4.w;
      }
      bias_eff[e] = acc + b_merge[e];
      return;
    }
    if (bid >= 1344) {
      const int i = (bid - 1344) * 256 + t;  // 0..65535 float4 ids
      const int e = i >> 7;
      const int c4 = (i & 127) * 4;
      float4 v = *(const float4*)&Wm[(size_t)e * 1024 + c4];
      f16x4 o = {(_Float16)v.x, (_Float16)v.y, (_Float16)v.z, (_Float16)v.w};
      *(f16x4*)&W16[(size_t)e * 1024 + c4] = o;
      return;
    }
    // ---------------- wsplit part ----------------
    const int gid = bid - GBLK;                // 0..1023
    const int db = (gid & 15) * 32;
    const int eb = ((gid >> 4) & 15) * 32;
    const int kc = gid >> 8;                   // 0..3
    float(*As)[33] = (float(*)[33])smem;
    float(*Bs)[33] = (float(*)[33])(smem + 32 * 33 * 4);
    const int tx = t % 16, ty = t / 16;
    const int lr = t / 8;
    const int lc = (t % 8) * 4;
    float a00 = 0.f, a01 = 0.f, a10 = 0.f, a11 = 0.f;
    for (int c0 = kc * 128; c0 < kc * 128 + 128; c0 += 32) {
      float4 av = *(const float4*)&Wm[(size_t)(eb + lr) * 1024 + 512 + c0 + lc];
      float4 bv = *(const float4*)&Wmsg[(size_t)(c0 + lr) * 512 + db + lc];
      As[lr][lc + 0] = av.x; As[lr][lc + 1] = av.y;
      As[lr][lc + 2] = av.z; As[lr][lc + 3] = av.w;
      Bs[lr][lc + 0] = bv.x; Bs[lr][lc + 1] = bv.y;
      Bs[lr][lc + 2] = bv.z; Bs[lr][lc + 3] = bv.w;
      __syncthreads();
#pragma unroll
      for (int kk = 0; kk < 32; kk++) {
        float x0 = As[2 * ty + 0][kk], x1 = As[2 * ty + 1][kk];
        float y0 = Bs[kk][2 * tx + 0], y1 = Bs[kk][2 * tx + 1];
        a00 += x0 * y0; a01 += x0 * y1;
        a10 += x1 * y0; a11 += x1 * y1;
      }
      __syncthreads();
    }
    float* base = W2p + (size_t)kc * 512 * 512;
    base[(size_t)(eb + 2 * ty + 0) * 512 + db + 2 * tx + 0] = a00;
    base[(size_t)(eb + 2 * ty + 0) * 512 + db + 2 * tx + 1] = a01;
    base[(size_t)(eb + 2 * ty + 1) * 512 + db + 2 * tx + 0] = a10;
    base[(size_t)(eb + 2 * ty + 1) * 512 + db + 2 * tx + 1] = a11;
    return;
  }

  // ---------------- gram part (upper triangle) ----------------
  const int work = (bid & 7) * (GBLK / 8) + (bid >> 3);
  const int s = work / GPAIRS;                // 0..31 (4 per XCD)
  const int pr = work % GPAIRS;
  const int bx = kBx[pr];
  const int by = kBy[pr];
  const int I = bx * 64;
  const int J = by * 64;
  const bool duty = (bx == by);
  const int lane = t & 63;
  const int w = t >> 6;                       // 0..3
  char* sHiI = smem;                          // 64 x 128 B = 8 KB each
  char* sHiJ = smem + 8192;
  char* sLoJ = smem + 16384;
  char* sLoI = smem + 24576;
  const int wm = w >> 1, wn = w & 1;
  const int rlane = lane & 15;
  const int kq = lane >> 4;

  f32x4 c1[2][2] = {};
  f32x4 c2[2][2] = {};
  f32x4 c3[2][2] = {};

  const float* hI = h + (size_t)I * RBD + (size_t)s * 1024;
  const float* hJ = h + (size_t)J * RBD + (size_t)s * 1024;
  const int frow = t >> 4;                    // staging row base (per u: +16)
  const int fc4 = t & 15;                     // float4-chunk in 64-col tile

  float4 rI[4], rJ[4];
  // prologue: kt=0 tiles (duty blocks skip the duplicate J stream)
#pragma unroll
  for (int u = 0; u < 4; ++u) {
    const int row = u * 16 + frow;
    rI[u] = *(const float4*)&hI[(size_t)row * RBD + fc4 * 4];
    if (!duty) rJ[u] = *(const float4*)&hJ[(size_t)row * RBD + fc4 * 4];
  }

  for (int kt = 0; kt < 16; ++kt) {
    if (kt) __syncthreads();  // prior MFMA reads done before overwrite
    // ---- cvt + ds_write current tiles (+ A16 duty write) ----
#pragma unroll
    for (int u = 0; u < 4; ++u) {
      const int row = u * 16 + frow;
      const int boff =
          row * 128 + (((fc4 >> 1) ^ (row & 7)) << 4) + (fc4 & 1) * 8;
      float4 vI = rI[u];
      f16x4 hiI = {(_Float16)vI.x, (_Float16)vI.y, (_Float16)vI.z,
                   (_Float16)vI.w};
      f16x4 loI = {(_Float16)(vI.x - (float)hiI[0]),
                   (_Float16)(vI.y - (float)hiI[1]),
                   (_Float16)(vI.z - (float)hiI[2]),
                   (_Float16)(vI.w - (float)hiI[3])};
      *(f16x4*)(sHiI + boff) = hiI;
      *(f16x4*)(sLoI + boff) = loI;
      if (duty) {
        *(f16x4*)(sHiJ + boff) = hiI;
        *(f16x4*)(sLoJ + boff) = loI;
        *(f16x4*)&A16[(size_t)(J + row) * RBD + (size_t)s * 1024 + kt * 64 +
                      fc4 * 4] = hiI;
      } else {
        float4 vJ = rJ[u];
        f16x4 hiJ = {(_Float16)vJ.x, (_Float16)vJ.y, (_Float16)vJ.z,
                     (_Float16)vJ.w};
        f16x4 loJ = {(_Float16)(vJ.x - (float)hiJ[0]),
                     (_Float16)(vJ.y - (float)hiJ[1]),
                     (_Float16)(vJ.z - (float)hiJ[2]),
                     (_Float16)(vJ.w - (float)hiJ[3])};
        *(f16x4*)(sHiJ + boff) = hiJ;
        *(f16x4*)(sLoJ + boff) = loJ;
      }
    }
    __syncthreads();
    // ---- issue next-tile loads (fly during the MFMA phase) ----
    if (kt < 15) {
#pragma unroll
      for (int u = 0; u < 4; ++u) {
        const int row = u * 16 + frow;
        rI[u] =
            *(const float4*)&hI[(size_t)row * RBD + (kt + 1) * 64 + fc4 * 4];
        if (!duty)
          rJ[u] =
              *(const float4*)&hJ[(size_t)row * RBD + (kt + 1) * 64 + fc4 * 4];
      }
    }
    // ---- MFMA phase: c1 = HiI.HiJ^T, c2 = HiI.LoJ^T, c3 = LoI.HiJ^T ----
#pragma unroll
    for (int ks = 0; ks < 2; ++ks) {
      f16x8 ai[2], li[2], bj[2], lj[2];
#pragma unroll
      for (int i = 0; i < 2; ++i) {
        const int row = wm * 32 + i * 16 + rlane;
        const int slot = (ks * 4 + kq) ^ (row & 7);
        ai[i] = *(const f16x8*)(sHiI + row * 128 + slot * 16);
        li[i] = *(const f16x8*)(sLoI + row * 128 + slot * 16);
      }
#pragma unroll
      for (int j = 0; j < 2; ++j) {
        const int row = wn * 32 + j * 16 + rlane;
        const int slot = (ks * 4 + kq) ^ (row & 7);
        bj[j] = *(const f16x8*)(sHiJ + row * 128 + slot * 16);
        lj[j] = *(const f16x8*)(sLoJ + row * 128 + slot * 16);
      }
#pragma unroll
      for (int i = 0; i < 2; ++i)
#pragma unroll
        for (int j = 0; j < 2; ++j) {
          c1[i][j] = __builtin_amdgcn_mfma_f32_16x16x32_f16(ai[i], bj[j],
                                                            c1[i][j], 0, 0, 0);
          c2[i][j] = __builtin_amdgcn_mfma_f32_16x16x32_f16(ai[i], lj[j],
                                                            c2[i][j], 0, 0, 0);
          c3[i][j] = __builtin_amdgcn_mfma_f32_16x16x32_f16(li[i], bj[j],
                                                            c3[i][j], 0, 0, 0);
        }
    }
  }

  f32x4 cs[2][2];
#pragma unroll
  for (int i = 0; i < 2; ++i)
#pragma unroll
    for (int j = 0; j < 2; ++j)
      cs[i][j] = c1[i][j] + c2[i][j] + c3[i][j];

  // normal orientation
#pragma unroll
  for (int i = 0; i < 2; ++i) {
#pragma unroll
    for (int reg = 0; reg < 4; ++reg) {
      const int gr = I + wm * 32 + i * 16 + kq * 4 + reg;
      const size_t base = ((size_t)s * 256 + gr) * 256 + J + wn * 32 + rlane;
#pragma unroll
      for (int j = 0; j < 2; ++j) Cp[base + j * 16] = cs[i][j][reg];
    }
  }
  // transposed orientation (off-diagonal only): float4 per lane
  if (!duty) {
#pragma unroll
    for (int i = 0; i < 2; ++i)
#pragma unroll
      for (int j = 0; j < 2; ++j) {
        const int gc = J + wn * 32 + j * 16 + rlane;
        const int gr0 = I + wm * 32 + i * 16 + kq * 4;
        *(f32x4*)&Cp[((size_t)s * 256 + gc) * 256 + gr0] = cs[i][j];
      }
  }
}

// ---------------------------------------------------------------------------
// Kernel 2 (fin): fused reduce+topk+neighbor-mean and W2 finisher,
// 1280 blocks x 256 thr.
//  - blocks [0,256): block r: T[j] = sum_s Csum[s][r][j] (coalesced), stable
//    top-4 over nbrs (strict >, first index wins = lax.top_k ties), then
//    Am16[r] = packed-fp16 mean of the 4 selected A16 regions (L3-warm).
//  - blocks [256,1280): W16[e][512+d] = fp16(sum_kc W2p[kc][e][d])
// ---------------------------------------------------------------------------
__global__ __launch_bounds__(256) void fin_kernel(
    const float* __restrict__ Cp, const int* __restrict__ nbrs,
    const float* __restrict__ W2p, const _Float16* __restrict__ A16,
    _Float16* __restrict__ Am16, int* __restrict__ sel,
    float* __restrict__ fanin, _Float16* __restrict__ W16) {
  const int bx = blockIdx.x;
  const int t = threadIdx.x;
  if (bx < 256) {
    const int r = bx;
    __shared__ float sims_all[256];
    __shared__ int nb_s[N_];
    __shared__ int sel_sm[K_];
    const float* base = Cp + (size_t)r * 256 + t;
    float acc = 0.f;
#pragma unroll 8
    for (int s = 0; s < GSLICES; ++s) acc += base[(size_t)s * 65536];
    sims_all[t] = acc;
    if (t < N_) nb_s[t] = nbrs[r * N_ + t];
    __syncthreads();
    if (t == 0) {
      float sims_s[N_];
#pragma unroll
      for (int n = 0; n < N_; ++n) sims_s[n] = sims_all[nb_s[n]];
      unsigned used = 0;
#pragma unroll
      for (int k = 0; k < K_; k++) {
        float best = -3.0e38f;
        int bi = 0;
        for (int nn = 0; nn < N_; nn++) {
          if (used & (1u << nn)) continue;
          float vv = sims_s[nn];
          if (vv > best) { best = vv; bi = nn; }
        }
        used |= 1u << bi;
        const int sj = nb_s[bi];
        sel[r * K_ + k] = sj;
        sel_sm[k] = sj;
      }
      if (r == 0) *fanin = 4.0f;
    }
    __syncthreads();
    const _Float16* g0 = A16 + (size_t)sel_sm[0] * RBD;
    const _Float16* g1 = A16 + (size_t)sel_sm[1] * RBD;
    const _Float16* g2 = A16 + (size_t)sel_sm[2] * RBD;
    const _Float16* g3 = A16 + (size_t)sel_sm[3] * RBD;
    _Float16* dst = Am16 + (size_t)r * RBD;
#pragma unroll 4
    for (int i = t; i < RBD / 8; i += 256) {  // 4096 f16x8 chunks
      const size_t off = (size_t)i * 8;
      f16x8 q0 = *(const f16x8*)&g0[off];
      f16x8 q1 = *(const f16x8*)&g1[off];
      f16x8 q2 = *(const f16x8*)&g2[off];
      f16x8 q3 = *(const f16x8*)&g3[off];
      f16x8 m = ((q0 + q1) + (q2 + q3)) * (_Float16)0.25f;
      *(f16x8*)&dst[off] = m;
    }
  } else {
    const int i = (bx - 256) * 256 + t;
    const int e = i >> 9;
    const int d = i & 511;
    float acc = 0.f;
#pragma unroll
    for (int kc = 0; kc < 4; ++kc)
      acc += W2p[(size_t)kc * 512 * 512 + (size_t)e * 512 + d];
    W16[(size_t)e * 1024 + 512 + d] = (_Float16)acc;
  }
}

// ---------------------------------------------------------------------------
// Kernel 3: fp16 MFMA GEMM, 2-phase pipelined (T3 minimum recipe).
// Double-buffered LDS (64 KB); each iteration stages kt+1's tiles via
// global_load_lds into buf^1 BEFORE computing buf, so loads fly across the
// MFMA phase; one __syncthreads per k-step provides both orderings.
// Tile 128x128, 8 waves (2m x 4n), 512 thr, grid 512 = 2 blk/CU, XCD swizzle.
// ---------------------------------------------------------------------------
__global__ __launch_bounds__(512, 2) void mfma_gemm_kernel(
    const _Float16* __restrict__ A16, const _Float16* __restrict__ Am16,
    const _Float16* __restrict__ W16, const float* __restrict__ bias,
    float* __restrict__ out) {
  const int t = threadIdx.x;
  const int lane = t & 63;
  const int w = t >> 6;                  // 0..7
  const int bid = blockIdx.x;
  const int work = (bid & 7) * 64 + (bid >> 3);
  const int eb = (work & 3) * 128;
  const int mt = work >> 2;              // 0..127
  const int m0 = mt * 128;
  __shared__ char smemA[2][128 * 128];   // 32 KB
  __shared__ char smemW[2][128 * 128];   // 32 KB
  const int wm = w >> 2, wn = w & 3;
  const int rlane = lane & 15;
  const int kq = lane >> 4;

  f32x4 acc[4][2] = {};

  const char* Ab = (const char*)A16;
  const char* Amb = (const char*)Am16;
  const char* Wb = (const char*)W16;

  const int f0 = t, f1 = 512 + t;
  const int row0 = f0 >> 3, slot0 = (f0 & 7) ^ (row0 & 7);
  const int row1 = f1 >> 3, slot1 = (f1 & 7) ^ (row1 & 7);

#define GEMM_STAGE(buf, kt)                                                    \
  {                                                                            \
    const char* ga0 =                                                          \
        ((kt) < 8)                                                             \
            ? Ab + ((size_t)(m0 + row0) * 1024 + (kt) * 128 + slot0 * 16)      \
            : Amb +                                                            \
                  ((size_t)(m0 + row0) * 1024 + ((kt)-8) * 128 + slot0 * 16);  \
    __builtin_amdgcn_global_load_lds((const g_u32*)ga0,                        \
                                     (l_u32*)(smemA[buf] + w * 1024), 16, 0,   \
                                     0);                                       \
    const char* gw0 =                                                          \
        Wb + ((size_t)(eb + row0) * 2048 + (kt) * 128 + slot0 * 16);           \
    __builtin_amdgcn_global_load_lds((const g_u32*)gw0,                        \
                                     (l_u32*)(smemW[buf] + w * 1024), 16, 0,   \
                                     0);                                       \
    const char* ga1 =                                                          \
        ((kt) < 8)                                                             \
            ? Ab + ((size_t)(m0 + row1) * 1024 + (kt) * 128 + slot1 * 16)      \
            : Amb +                                                            \
                  ((size_t)(m0 + row1) * 1024 + ((kt)-8) * 128 + slot1 * 16);  \
    __builtin_amdgcn_global_load_lds(                                          \
        (const g_u32*)ga1, (l_u32*)(smemA[buf] + 8192 + w * 1024), 16, 0, 0);  \
    const char* gw1 =                                                          \
        Wb + ((size_t)(eb + row1) * 2048 + (kt) * 128 + slot1 * 16);           \
    __builtin_amdgcn_global_load_lds(                                          \
        (const g_u32*)gw1, (l_u32*)(smemW[buf] + 8192 + w * 1024), 16, 0, 0);  \
  }

  GEMM_STAGE(0, 0);
  __syncthreads();  // buf0 ready (compiler drains vmcnt before barrier)

  int cur = 0;
  for (int kt = 0; kt < 16; ++kt) {
    if (kt < 15) GEMM_STAGE(cur ^ 1, kt + 1);  // next-tile loads in flight
    // ---- compute from buf[cur] ----
#pragma unroll
    for (int ks = 0; ks < 2; ++ks) {
      f16x8 a[4], b[2];
#pragma unroll
      for (int i = 0; i < 4; ++i) {
        const int row = wm * 64 + i * 16 + rlane;
        const int slot = (ks * 4 + kq) ^ (row & 7);
        a[i] = *(const f16x8*)(smemA[cur] + row * 128 + slot * 16);
      }
#pragma unroll
      for (int j = 0; j < 2; ++j) {
        const int row = wn * 32 + j * 16 + rlane;
        const int slot = (ks * 4 + kq) ^ (row & 7);
        b[j] = *(const f16x8*)(smemW[cur] + row * 128 + slot * 16);
      }
#pragma unroll
      for (int i = 0; i < 4; ++i)
#pragma unroll
        for (int j = 0; j < 2; ++j)
          acc[i][j] = __builtin_amdgcn_mfma_f32_16x16x32_f16(a[i], b[j],
                                                             acc[i][j], 0, 0, 0);
    }
    __syncthreads();  // drains next-tile loads; orders reads before overwrite
    cur ^= 1;
  }
#undef GEMM_STAGE

  float bj[2];
#pragma unroll
  for (int j = 0; j < 2; ++j) bj[j] = bias[eb + wn * 32 + j * 16 + rlane];
#pragma unroll
  for (int i = 0; i < 4; ++i) {
#pragma unroll
    for (int reg = 0; reg < 4; ++reg) {
      const size_t m = (size_t)m0 + wm * 64 + i * 16 + kq * 4 + reg;
      float* po = out + m * 512 + eb + wn * 32 + rlane;
#pragma unroll
      for (int j = 0; j < 2; ++j) po[j * 16] = acc[i][j][reg] + bj[j];
    }
  }
}

// ---------------------------------------------------------------------------
// Fallback fp32 path (small workspace): round-1 kernels.
// ---------------------------------------------------------------------------
__global__ __launch_bounds__(256) void bias_kernel(
    const float* __restrict__ Wm, const float* __restrict__ b_msg,
    const float* __restrict__ b_merge, float* __restrict__ bias_eff) {
  const int e = blockIdx.x * 256 + threadIdx.x;
  const float4* bp = (const float4*)b_msg;
  const float4* wp = (const float4*)&Wm[(size_t)e * 1024 + 512];
  float acc = 0.f;
  for (int c = 0; c < 128; c++) {
    float4 b4 = bp[c], w4 = wp[c];
    acc += b4.x * w4.x + b4.y * w4.y + b4.z * w4.z + b4.w * w4.w;
  }
  bias_eff[e] = acc + b_merge[e];
}

__global__ __launch_bounds__(256) void sims_topk_kernel(
    const float* __restrict__ h, const int* __restrict__ nbrs,
    int* __restrict__ sel, float* __restrict__ fanin) {
  const int r = blockIdx.x;
  const int t = threadIdx.x;
  const int lane = t & 63;
  const int wave = t >> 6;
  __shared__ float sims_s[N_];
  __shared__ int nb_s[N_];
  if (t < N_) nb_s[t] = nbrs[r * N_ + t];
  __syncthreads();
  const int n0 = wave * 4;
  const float4* hr  = (const float4*)(h + (size_t)r * RBD);
  const float4* hn0 = (const float4*)(h + (size_t)nb_s[n0 + 0] * RBD);
  const float4* hn1 = (const float4*)(h + (size_t)nb_s[n0 + 1] * RBD);
  const float4* hn2 = (const float4*)(h + (size_t)nb_s[n0 + 2] * RBD);
  const float4* hn3 = (const float4*)(h + (size_t)nb_s[n0 + 3] * RBD);
  float a0 = 0.f, a1 = 0.f, a2 = 0.f, a3 = 0.f;
  for (int i = lane; i < RBD / 4; i += 64) {
    float4 x = hr[i];
    float4 y0 = hn0[i], y1 = hn1[i], y2 = hn2[i], y3 = hn3[i];
    a0 += x.x * y0.x + x.y * y0.y + x.z * y0.z + x.w * y0.w;
    a1 += x.x * y1.x + x.y * y1.y + x.z * y1.z + x.w * y1.w;
    a2 += x.x * y2.x + x.y * y2.y + x.z * y2.z + x.w * y2.w;
    a3 += x.x * y3.x + x.y * y3.y + x.z * y3.z + x.w * y3.w;
  }
  float v[4] = {a0, a1, a2, a3};
#pragma unroll
  for (int n = 0; n < 4; n++) {
    float x = v[n];
#pragma unroll
    for (int off = 32; off > 0; off >>= 1) x += __shfl_down(x, off);
    if (lane == 0) sims_s[n0 + n] = x;
  }
  __syncthreads();
  if (t == 0) {
    unsigned used = 0;
#pragma unroll
    for (int k = 0; k < K_; k++) {
      float best = -3.0e38f;
      int bi = 0;
      for (int n = 0; n < N_; n++) {
        if (used & (1u << n)) continue;
        float vv = sims_s[n];
        if (vv > best) { best = vv; bi = n; }
      }
      used |= 1u << bi;
      sel[r * K_ + k] = nb_s[bi];
    }
    if (r == 0) *fanin = 4.0f;
  }
}

__global__ __launch_bounds__(256) void w2eff_f32_kernel(
    const float* __restrict__ Wm, const float* __restrict__ Wmsg,
    float* __restrict__ W2) {
  __shared__ float As[32][33];
  __shared__ float Bs[32][33];
  const int t = threadIdx.x;
  const int eb = blockIdx.y * 32;
  const int db = blockIdx.x * 32;
  const int tx = t % 16, ty = t / 16;
  const int lr = t / 8;
  const int lc = (t % 8) * 4;
  float a00 = 0.f, a01 = 0.f, a10 = 0.f, a11 = 0.f;
  for (int c0 = 0; c0 < 512; c0 += 32) {
    float4 av = *(const float4*)&Wm[(size_t)(eb + lr) * 1024 + 512 + c0 + lc];
    float4 bv = *(const float4*)&Wmsg[(size_t)(c0 + lr) * 512 + db + lc];
    As[lr][lc + 0] = av.x; As[lr][lc + 1] = av.y;
    As[lr][lc + 2] = av.z; As[lr][lc + 3] = av.w;
    Bs[lr][lc + 0] = bv.x; Bs[lr][lc + 1] = bv.y;
    Bs[lr][lc + 2] = bv.z; Bs[lr][lc + 3] = bv.w;
    __syncthreads();
#pragma unroll
    for (int kk = 0; kk < 32; kk++) {
      float x0 = As[2 * ty + 0][kk], x1 = As[2 * ty + 1][kk];
      float y0 = Bs[kk][2 * tx + 0], y1 = Bs[kk][2 * tx + 1];
      a00 += x0 * y0; a01 += x0 * y1;
      a10 += x1 * y0; a11 += x1 * y1;
    }
    __syncthreads();
  }
  W2[(size_t)(eb + 2 * ty + 0) * 512 + db + 2 * tx + 0] = a00;
  W2[(size_t)(eb + 2 * ty + 0) * 512 + db + 2 * tx + 1] = a01;
  W2[(size_t)(eb + 2 * ty + 1) * 512 + db + 2 * tx + 0] = a10;
  W2[(size_t)(eb + 2 * ty + 1) * 512 + db + 2 * tx + 1] = a11;
}

__global__ __launch_bounds__(256) void fused_gemm_f32_kernel(
    const float* __restrict__ h, const int* __restrict__ sel,
    const float* __restrict__ Wm, const float* __restrict__ W2,
    const float* __restrict__ bias_eff, float* __restrict__ out) {
  const int r = blockIdx.y;
  const int eb = blockIdx.x * 256;
  const int t = threadIdx.x;
  __shared__ float As[64][33];
  __shared__ float Ws[256][33];
  __shared__ int sel_s[K_];
  if (t < K_) sel_s[t] = sel[r * K_ + t];
  __syncthreads();
  const size_t hr = (size_t)r * RBD;
  const size_t s0 = (size_t)sel_s[0] * RBD;
  const size_t s1 = (size_t)sel_s[1] * RBD;
  const size_t s2 = (size_t)sel_s[2] * RBD;
  const size_t s3 = (size_t)sel_s[3] * RBD;
  const int tb = t % 8;
  const int te = t / 8;
  const int ab = t / 4;
  const int ac = (t % 4) * 8;
  float acc[8][8] = {};
  for (int d0 = 0; d0 < 1024; d0 += 32) {
    if (d0 < 512) {
      const float* src = h + hr + (size_t)ab * 512 + d0 + ac;
      float4 v0 = *(const float4*)(src);
      float4 v1 = *(const float4*)(src + 4);
      As[ab][ac + 0] = v0.x; As[ab][ac + 1] = v0.y;
      As[ab][ac + 2] = v0.z; As[ab][ac + 3] = v0.w;
      As[ab][ac + 4] = v1.x; As[ab][ac + 5] = v1.y;
      As[ab][ac + 6] = v1.z; As[ab][ac + 7] = v1.w;
    } else {
      const size_t off = (size_t)ab * 512 + (d0 - 512) + ac;
      const float* p0 = h + s0 + off;
      const float* p1 = h + s1 + off;
      const float* p2 = h + s2 + off;
      const float* p3 = h + s3 + off;
      float4 q0 = *(const float4*)p0, q0b = *(const float4*)(p0 + 4);
      float4 q1 = *(const float4*)p1, q1b = *(const float4*)(p1 + 4);
      float4 q2 = *(const float4*)p2, q2b = *(const float4*)(p2 + 4);
      float4 q3 = *(const float4*)p3, q3b = *(const float4*)(p3 + 4);
      As[ab][ac + 0] = 0.25f * (q0.x + q1.x + q2.x + q3.x);
      As[ab][ac + 1] = 0.25f * (q0.y + q1.y + q2.y + q3.y);
      As[ab][ac + 2] = 0.25f * (q0.z + q1.z + q2.z + q3.z);
      As[ab][ac + 3] = 0.25f * (q0.w + q1.w + q2.w + q3.w);
      As[ab][ac + 4] = 0.25f * (q0b.x + q1b.x + q2b.x + q3b.x);
      As[ab][ac + 5] = 0.25f * (q0b.y + q1b.y + q2b.y + q3b.y);
      As[ab][ac + 6] = 0.25f * (q0b.z + q1b.z + q2b.z + q3b.z);
      As[ab][ac + 7] = 0.25f * (q0b.w + q1b.w + q2b.w + q3b.w);
    }
    {
      const float* src = (d0 < 512)
          ? (Wm + (size_t)(eb + t) * 1024 + d0)
          : (W2 + (size_t)(eb + t) * 512 + (d0 - 512));
#pragma unroll
      for (int j = 0; j < 8; j++) {
        float4 v = *(const float4*)(src + 4 * j);
        Ws[t][4 * j + 0] = v.x; Ws[t][4 * j + 1] = v.y;
        Ws[t][4 * j + 2] = v.z; Ws[t][4 * j + 3] = v.w;
      }
    }
    __syncthreads();
#pragma unroll
    for (int kk = 0; kk < 32; kk++) {
      float a[8], wv[8];
#pragma unroll
      for (int i = 0; i < 8; i++) a[i] = As[tb + 8 * i][kk];
#pragma unroll
      for (int j = 0; j < 8; j++) wv[j] = Ws[te + 32 * j][kk];
#pragma unroll
      for (int i = 0; i < 8; i++)
#pragma unroll
        for (int j = 0; j < 8; j++) acc[i][j] += a[i] * wv[j];
    }
    __syncthreads();
  }
  float be[8];
#pragma unroll
  for (int j = 0; j < 8; j++) be[j] = bias_eff[eb + te + 32 * j];
#pragma unroll
  for (int i = 0; i < 8; i++) {
    const int b = tb + 8 * i;
#pragma unroll
    for (int j = 0; j < 8; j++) {
      const int e = eb + te + 32 * j;
      out[hr + (size_t)b * 512 + e] = acc[i][j] + be[j];
    }
  }
}

// ---------------------------------------------------------------------------
extern "C" void kernel_launch(void* const* d_in, const int* in_sizes, int n_in,
                              void* d_out, int out_size, void* d_ws,
                              size_t ws_size, hipStream_t stream) {
  const float* h       = (const float*)d_in[0];
  const int*   nbrs    = (const int*)d_in[1];
  const float* W_msg   = (const float*)d_in[2];
  const float* b_msg   = (const float*)d_in[3];
  const float* W_merge = (const float*)d_in[4];
  const float* b_merge = (const float*)d_in[5];
  float* out = (float*)d_out;
  char* ws = (char*)d_ws;

  const size_t SZ_PART = (size_t)GSLICES * 256 * 256 * 4;  // 8.39 MB
  const size_t SZ_A = (size_t)M_TOT * 512 * 2;             // 16.78 MB each
  const size_t SZ_W = (size_t)512 * 1024 * 2;              // 1 MB
  const size_t SZ_W2P = (size_t)4 * 512 * 512 * 4;         // 4 MB
  size_t off = 0;
  int*      sel      = (int*)(ws + off);      off += 4096;
  float*    bias_eff = (float*)(ws + off);    off += 4096;
  float*    Cp       = (float*)(ws + off);    off += SZ_PART;
  _Float16* A16      = (_Float16*)(ws + off); off += SZ_A;
  _Float16* Am16     = (_Float16*)(ws + off); off += SZ_A;
  _Float16* W16      = (_Float16*)(ws + off); off += SZ_W;
  float*    W2p      = (float*)(ws + off);    off += SZ_W2P;
  const size_t NEED = off;

  if (ws_size >= NEED) {
    gramx_kernel<<<1602, 256, 0, stream>>>(h, W_merge, W_msg, b_msg, b_merge,
                                           A16, Cp, W2p, W16, bias_eff);
    fin_kernel<<<1280, 256, 0, stream>>>(Cp, nbrs, W2p, A16, Am16, sel,
                                         out + OUT_ELEMS, W16);
    mfma_gemm_kernel<<<512, 512, 0, stream>>>(A16, Am16, W16, bias_eff, out);
  } else {
    int*   fsel     = (int*)ws;
    float* W2       = (float*)(ws + 4096);
    float* fbias    = (float*)(ws + 4096 + 512 * 512 * 4);
    sims_topk_kernel<<<R_, 256, 0, stream>>>(h, nbrs, fsel, out + OUT_ELEMS);
    bias_kernel<<<2, 256, 0, stream>>>(W_merge, b_msg, b_merge, fbias);
    w2eff_f32_kernel<<<dim3(16, 16), 256, 0, stream>>>(W_merge, W_msg, W2);
    fused_gemm_f32_kernel<<<dim3(2, R_), 256, 0, stream>>>(h, fsel, W_merge,
                                                           W2, fbias, out);
  }
}